// Round 12
// baseline (222.418 us; speedup 1.0000x reference)
//
#include <hip/hip_runtime.h>

#define NB 64      // batch
#define SEQ 305    // sequence length
#define DIM 2048   // hidden
#define NP 256     // patches
#define NT 48      // task tokens
#define NKEEP 128  // kept patches
#define SOUT 177   // 1 + 128 + 48
#define KS 32      // d-depth per LDS stage

static_assert(1 + NP + NT == SEQ, "layout");

constexpr float kScale = 0.022097086912079608f;  // 1/sqrt(2048)

// ---------------------------------------------------------------------------
// K1a: R8-exact (measured 103 us, VGPR 128). grid (1 + 2*ndc, 64), 128 thr.
// x==0: fused static copy. Else: xi=x-1, dci=xi>>1, pt=xi&1.
// Tile 128p x 48t x dchunk, micro-tile 8x6, KS=32 (full 128-B rows),
// [d][row] LDS stride 140, register-staged prefetch, 2 barriers/chunk.
// ---------------------------------------------------------------------------
__global__ __launch_bounds__(128) void k1a_partial_gemm(
    const float* __restrict__ tokens, float* __restrict__ rpart,
    float* __restrict__ ssqP, float* __restrict__ ssqT,
    float* __restrict__ out0, int ndc, int dchunk) {
  const int b = blockIdx.y;
  const int t = threadIdx.x;

  if (blockIdx.x == 0) {
    // copy cls (row 0 -> 0) and task rows (257..304 -> 129..176)
#pragma unroll 2
    for (int l = 0; l < 196; ++l) {
      int u = l * 128 + t;  // 49 rows * 512 f4
      int row = u >> 9, c = u & 511;
      int srow = (row == 0) ? 0 : (256 + row);
      int drow = (row == 0) ? 0 : (128 + row);
      *(float4*)(out0 + ((size_t)b * SOUT + drow) * DIM + (size_t)c * 4) =
          *(const float4*)(tokens + ((size_t)b * SEQ + srow) * DIM + (size_t)c * 4);
    }
    return;
  }

  const int xi = blockIdx.x - 1;
  const int dci = xi >> 1;
  const int pt = xi & 1;
  const int pg = t >> 3;  // 0..15: p-rows pg*8..pg*8+7 (of this 128-half)
  const int tg = t & 7;   // 0..7:  t-cols tg*6..tg*6+5

  __shared__ __align__(16) float pC[KS][140];  // [d][p-row], stride 140
  __shared__ __align__(16) float tC[KS][64];   // [d][t-slot]: row r at (r/6)*8+r%6

  const float* pbase =
      tokens + ((size_t)b * SEQ + 1 + pt * 128) * DIM + (size_t)dci * dchunk;
  const float* tbase =
      tokens + ((size_t)b * SEQ + 1 + NP) * DIM + (size_t)dci * dchunk;

  float4 st[11];
  float acc[8][6] = {};
  float ssqa[11] = {};
  const int nchunk = dchunk / KS;

  // staging map: u = t + 128*l. l=0..7: p (row=u>>3 in 0..127, c8=u&7);
  // l=8..10: t (v=u-1024: row=v>>3 in 0..47, c8=v&7).
  auto gload = [&](int ck) {
#pragma unroll
    for (int l = 0; l < 11; ++l) {
      int u = t + 128 * l;
      if (u < 1024) {
        int row = u >> 3, c8 = u & 7;
        st[l] = *(const float4*)(pbase + (size_t)row * DIM + ck * KS + c8 * 4);
      } else {
        int v = u - 1024;
        int row = v >> 3, c8 = v & 7;
        st[l] = *(const float4*)(tbase + (size_t)row * DIM + ck * KS + c8 * 4);
      }
    }
  };
  auto lwrite = [&]() {
#pragma unroll
    for (int l = 0; l < 11; ++l) {
      int u = t + 128 * l;
      float4 v = st[l];
      if (u < 1024) {
        int row = u >> 3, c8 = u & 7;
        pC[c8 * 4 + 0][row] = v.x;
        pC[c8 * 4 + 1][row] = v.y;
        pC[c8 * 4 + 2][row] = v.z;
        pC[c8 * 4 + 3][row] = v.w;
        ssqa[l] += v.x * v.x + v.y * v.y + v.z * v.z + v.w * v.w;
      } else {
        int vv = u - 1024;
        int row = vv >> 3, c8 = vv & 7;
        int slot = (row / 6) * 8 + (row % 6);
        tC[c8 * 4 + 0][slot] = v.x;
        tC[c8 * 4 + 1][slot] = v.y;
        tC[c8 * 4 + 2][slot] = v.z;
        tC[c8 * 4 + 3][slot] = v.w;
        ssqa[l] += v.x * v.x + v.y * v.y + v.z * v.z + v.w * v.w;
      }
    }
  };

  gload(0);
  for (int ck = 0; ck < nchunk; ++ck) {
    __syncthreads();  // previous compute done reading LDS
    lwrite();
    if (ck + 1 < nchunk) gload(ck + 1);  // prefetch overlaps compute below
    __syncthreads();
#pragma unroll 4
    for (int dd = 0; dd < KS; ++dd) {
      float4 p0 = *(const float4*)&pC[dd][pg * 8];
      float4 p1 = *(const float4*)&pC[dd][pg * 8 + 4];
      float4 t0 = *(const float4*)&tC[dd][tg * 8];
      float2 t1 = *(const float2*)&tC[dd][tg * 8 + 4];
      float pa[8] = {p0.x, p0.y, p0.z, p0.w, p1.x, p1.y, p1.z, p1.w};
      float tb[6] = {t0.x, t0.y, t0.z, t0.w, t1.x, t1.y};
#pragma unroll
      for (int i = 0; i < 8; ++i)
#pragma unroll
        for (int j = 0; j < 6; ++j) acc[i][j] += pa[i] * tb[j];
    }
  }

  // partial R, transposed: rpart[(b*ndc+dci)][jg][256], cols pt*128+pg*8
  float* rp = rpart + ((size_t)b * ndc + dci) * (NT * NP) + pt * 128;
#pragma unroll
  for (int j = 0; j < 6; ++j) {
    int jg = tg * 6 + j;
    float4 v0 = {acc[0][j], acc[1][j], acc[2][j], acc[3][j]};
    float4 v1 = {acc[4][j], acc[5][j], acc[6][j], acc[7][j]};
    *(float4*)(rp + jg * NP + pg * 8) = v0;
    *(float4*)(rp + jg * NP + pg * 8 + 4) = v1;
  }

  // ssq: reduce across the 8 staging lanes of each row (fixed order)
#pragma unroll
  for (int l = 0; l < 11; ++l) {
    float s = ssqa[l];
    s += __shfl_down(s, 4, 8);
    s += __shfl_down(s, 2, 8);
    s += __shfl_down(s, 1, 8);
    ssqa[l] = s;
  }
  if ((t & 7) == 0) {
#pragma unroll
    for (int l = 0; l < 11; ++l) {
      int u = t + 128 * l;
      if (u < 1024) {
        ssqP[((size_t)b * ndc + dci) * NP + pt * 128 + (u >> 3)] = ssqa[l];
      } else {
        if (pt == 0)
          ssqT[((size_t)b * ndc + dci) * NT + ((u - 1024) >> 3)] = ssqa[l];
      }
    }
  }
}

// ---------------------------------------------------------------------------
// K1b: re-gridded to (16 pt, 64 b) x 256 thr, 16-row tiles. Sum ndc partials
// in the SAME fixed dci order (bitwise-identical to before), rms + softmax,
// write attnp = softmax*invT and rn = raw*invP. Inits umax.
// Thread (r = t>>4, c16 = t&15): accumulates cols c16*3..+2 of row pt*16+r;
// reads are 16-consecutive-float coalesced along r.
// ---------------------------------------------------------------------------
__global__ __launch_bounds__(256) void k1b_reduce_softmax(
    const float* __restrict__ rpart, const float* __restrict__ ssqP,
    const float* __restrict__ ssqT, float* __restrict__ attnp,
    float* __restrict__ rn, unsigned long long* __restrict__ umax, int ndc) {
  const int pt = blockIdx.x;  // 0..15: rows pt*16..pt*16+15
  const int b = blockIdx.y;
  const int t = threadIdx.x;
  const int r = t >> 4;    // 0..15
  const int c16 = t & 15;  // 0..15 -> cols c16*3..c16*3+2

  __shared__ float L[16][49];
  __shared__ float invPs[16];
  __shared__ float invTs[48];

  float a[3] = {};
  const float* rb = rpart + (size_t)b * ndc * (NT * NP) + pt * 16 + r;
  for (int dci = 0; dci < ndc; ++dci) {
    const float* rp = rb + (size_t)dci * (NT * NP);
#pragma unroll
    for (int k = 0; k < 3; ++k) a[k] += rp[(c16 * 3 + k) * NP];
  }
#pragma unroll
  for (int k = 0; k < 3; ++k) L[r][c16 * 3 + k] = a[k];

  if (t < 16) {
    float s = 0.f;
    for (int dci = 0; dci < ndc; ++dci)
      s += ssqP[((size_t)b * ndc + dci) * NP + pt * 16 + t];
    invPs[t] = 1.0f / sqrtf(s * (1.0f / 2048.0f) + 1e-6f);
    umax[(size_t)b * NP + pt * 16 + t] = 0ull;
  } else if (t < 64) {
    int j = t - 16;
    float s = 0.f;
    for (int dci = 0; dci < ndc; ++dci)
      s += ssqT[((size_t)b * ndc + dci) * NT + j];
    invTs[j] = 1.0f / sqrtf(s * (1.0f / 2048.0f) + 1e-6f);
  }
  __syncthreads();

  if (t < 16) {
    const float invp = invPs[t];
    float lg[48];
    float m = -3.4e38f;
#pragma unroll
    for (int j = 0; j < 48; ++j) {
      lg[j] = L[t][j] * invp * invTs[j] * kScale;
      m = fmaxf(m, lg[j]);
    }
    float s = 0.f;
#pragma unroll
    for (int j = 0; j < 48; ++j) {
      lg[j] = expf(lg[j] - m);
      s += lg[j];
    }
    const float is = 1.0f / s;
    float* ao = attnp + ((size_t)b * NP + pt * 16 + t) * NT;
    float* ro = rn + ((size_t)b * NP + pt * 16 + t) * NT;
#pragma unroll
    for (int j = 0; j < 48; ++j) ao[j] = lg[j] * is * invTs[j];
#pragma unroll
    for (int j = 0; j < 48; ++j) ro[j] = L[t][j] * invp;
  }
}

// ---------------------------------------------------------------------------
// K2: score[p][q] = sum_t attn'[p][t] * Rn[q][t], argmax over q folded in via
// packed (mono-float | ~q) atomicMax (order-independent -> deterministic).
// ---------------------------------------------------------------------------
__global__ __launch_bounds__(256) void k2_score_argmax(
    const float* __restrict__ attnp, const float* __restrict__ rn,
    unsigned long long* __restrict__ umax) {
  const int b = blockIdx.y;
  const int qt = blockIdx.x & 3;
  const int pb = blockIdx.x >> 2;
  const int t = threadIdx.x;
  const int tp = t >> 4, tq = t & 15;

  __shared__ float aS[48][68];
  __shared__ float rS[48][68];

  const float* ab = attnp + ((size_t)b * NP + pb * 64) * NT;
  const float* rb = rn + ((size_t)b * NP + qt * 64) * NT;
#pragma unroll
  for (int l = 0; l < 3; ++l) {
    int u = t + 256 * l;  // 64 rows x 12 f4
    int row = u / 12, c4 = u % 12;
    float4 v = *(const float4*)(ab + (size_t)row * NT + c4 * 4);
    aS[c4 * 4 + 0][row] = v.x;
    aS[c4 * 4 + 1][row] = v.y;
    aS[c4 * 4 + 2][row] = v.z;
    aS[c4 * 4 + 3][row] = v.w;
    float4 wv = *(const float4*)(rb + (size_t)row * NT + c4 * 4);
    rS[c4 * 4 + 0][row] = wv.x;
    rS[c4 * 4 + 1][row] = wv.y;
    rS[c4 * 4 + 2][row] = wv.z;
    rS[c4 * 4 + 3][row] = wv.w;
  }
  __syncthreads();

  float acc[4][4] = {};
#pragma unroll
  for (int k = 0; k < 48; ++k) {
    float4 av = *(const float4*)&aS[k][tp * 4];
    float4 rv = *(const float4*)&rS[k][tq * 4];
    float aa[4] = {av.x, av.y, av.z, av.w};
    float rr[4] = {rv.x, rv.y, rv.z, rv.w};
#pragma unroll
    for (int i = 0; i < 4; ++i)
#pragma unroll
      for (int j = 0; j < 4; ++j) acc[i][j] += aa[i] * rr[j];
  }

#pragma unroll
  for (int i = 0; i < 4; ++i) {
    float bs = acc[i][0];
    int bq = qt * 64 + tq * 4;
#pragma unroll
    for (int j = 1; j < 4; ++j) {
      float s = acc[i][j];
      int qq = qt * 64 + tq * 4 + j;
      if (s > bs) {  // strict > keeps smallest q on ties
        bs = s;
        bq = qq;
      }
    }
    unsigned us = __float_as_uint(bs);
    us = (us & 0x80000000u) ? ~us : (us | 0x80000000u);
    unsigned long long key =
        ((unsigned long long)us << 32) | (unsigned long long)(0xFFFFFFFFu - (unsigned)bq);
    for (int o = 8; o >= 1; o >>= 1) {
      unsigned long long ok = __shfl_xor(key, o, 16);
      if (ok > key) key = ok;
    }
    if (tq == 0) atomicMax(&umax[(size_t)b * NP + pb * 64 + tp * 4 + i], key);
  }
}

// ---------------------------------------------------------------------------
// K3: per batch: decode argmax, vote counts, exact rank (count desc, idx asc),
// keep rank<128, emit ascending; gather pos/mask in the same block.
// ---------------------------------------------------------------------------
__global__ __launch_bounds__(256) void k3_select_meta(
    const unsigned long long* __restrict__ umax, const int* __restrict__ pos,
    const int* __restrict__ msk, int* __restrict__ order,
    float* __restrict__ out1, float* __restrict__ out2) {
  const int b = blockIdx.x, t = threadIdx.x;
  __shared__ int cnt[256];
  __shared__ int kept[256];
  __shared__ int sorder[NKEEP];
  cnt[t] = 0;
  __syncthreads();
  unsigned long long key = umax[(size_t)b * NP + t];
  int q = (int)(0xFFFFFFFFu - (unsigned)(key & 0xFFFFFFFFull));
  atomicAdd(&cnt[q], 1);
  __syncthreads();
  const int c = cnt[t];
  int rank = 0;
  for (int u = 0; u < 256; ++u) {
    int cu = cnt[u];
    rank += (cu > c || (cu == c && u < t)) ? 1 : 0;
  }
  kept[t] = (rank < NKEEP) ? 1 : 0;
  __syncthreads();
  if (kept[t]) {
    int posn = 0;
    for (int u = 0; u < t; ++u) posn += kept[u];
    order[b * NKEEP + posn] = t;
    sorder[posn] = t;
  }
  __syncthreads();
  if (t < SOUT) {
    int src;
    if (t == 0) src = 0;
    else if (t < 1 + NKEEP) src = 1 + sorder[t - 1];
    else src = t + (NP - NKEEP);
    out1[b * SOUT + t] = (float)pos[b * SEQ + src];
    out2[b * SOUT + t] = (float)msk[b * SEQ + src];
  }
}

// ---------------------------------------------------------------------------
// K4: gather only the 128 kept patch rows (cls/task copied in k1a).
// ---------------------------------------------------------------------------
__global__ __launch_bounds__(256) void k4_gather_kept(
    const float* __restrict__ tokens, const int* __restrict__ order,
    float* __restrict__ out) {
  const int ki = blockIdx.x;  // 0..127
  const int b = blockIdx.y;
  const int t = threadIdx.x;
  const int src = 1 + order[b * NKEEP + ki];
  const float4* in4 = (const float4*)(tokens + ((size_t)b * SEQ + src) * DIM);
  float4* o4 = (float4*)(out + ((size_t)b * SOUT + 1 + ki) * DIM);
  o4[t] = in4[t];
  o4[t + 256] = in4[t + 256];
}

// ---------------------------------------------------------------------------
extern "C" void kernel_launch(void* const* d_in, const int* in_sizes, int n_in,
                              void* d_out, int out_size, void* d_ws,
                              size_t ws_size, hipStream_t stream) {
  const float* tokens = (const float*)d_in[0];
  const int* pos = (const int*)d_in[1];
  const int* msk = (const int*)d_in[2];

  float* out0 = (float*)d_out;
  float* out1 = out0 + (size_t)NB * SOUT * DIM;
  float* out2 = out1 + (size_t)NB * SOUT;

  // adaptive split-K depth by workspace size
  const size_t fixed = (size_t)(2 * NB * NP * NT) * 4 + (size_t)NB * NP * 8 +
                       (size_t)NB * NKEEP * 4;
  const size_t perndc = (size_t)NB * (NT * NP + NP + NT) * 4;
  int ndc = 16;
  while (ndc > 4 && fixed + (size_t)ndc * perndc > ws_size) ndc >>= 1;
  const int dchunk = DIM / ndc;

  char* ws = (char*)d_ws;
  float* attnp = (float*)ws;                 // NB*NP*NT
  float* rn = attnp + (size_t)NB * NP * NT;  // NB*NP*NT
  unsigned long long* umax = (unsigned long long*)(rn + (size_t)NB * NP * NT);
  int* order = (int*)(umax + (size_t)NB * NP);
  float* rpart = (float*)(order + (size_t)NB * NKEEP);  // NB*ndc*48*256
  float* ssqP = rpart + (size_t)NB * ndc * NT * NP;     // NB*ndc*256
  float* ssqT = ssqP + (size_t)NB * ndc * NP;           // NB*ndc*48

  k1a_partial_gemm<<<dim3(1 + 2 * ndc, NB), 128, 0, stream>>>(
      tokens, rpart, ssqP, ssqT, out0, ndc, dchunk);
  k1b_reduce_softmax<<<dim3(16, NB), 256, 0, stream>>>(rpart, ssqP, ssqT, attnp,
                                                       rn, umax, ndc);
  k2_score_argmax<<<dim3(16, NB), 256, 0, stream>>>(attnp, rn, umax);
  k3_select_meta<<<NB, 256, 0, stream>>>(umax, pos, msk, order, out1, out2);
  k4_gather_kept<<<dim3(NKEEP, NB), 256, 0, stream>>>(tokens, order, out0);
}

// Round 13
// 173.336 us; speedup vs baseline: 1.2832x; 1.2832x over previous
//
#include <hip/hip_runtime.h>

#define NB 64      // batch
#define SEQ 305    // sequence length
#define DIM 2048   // hidden
#define NP 256     // patches
#define NT 48      // task tokens
#define NKEEP 128  // kept patches
#define SOUT 177   // 1 + 128 + 48

static_assert(1 + NP + NT == SEQ, "layout");

constexpr float kScale = 0.022097086912079608f;  // 1/sqrt(2048)

typedef _Float16 f16;
typedef __attribute__((ext_vector_type(8))) _Float16 f16x8;
typedef __attribute__((ext_vector_type(4))) float f32x4;

// ---------------------------------------------------------------------------
// K1a: split-f16 MFMA partial GEMM. grid (1+ndc, 64), 256 thr (4 waves).
// x==0: fused static copy of cls+task rows. Else dci = x-1.
// Tile M=256 (all patches) x N=48 x dchunk. Per K32 chunk:
//   stage: fp32 -> (hi,lo) f16 split, interleaved [row][g*8] = {hi4,lo4}
//          (16B b128 writes, conflict-free); ssq accumulated on fp32.
//   compute: per wave 4 mfrags x 3 nfrags, 3 MFMAs each (hh, hl, lh) into
//          f32 acc. A,B frags: row = base+(lane&15), d0 = (lane>>4)*8 --
//          identical k-mapping on both operands => exact pairwise dot.
// Error ~5e-7 relative (22-bit mantissa), below the ~1e-6 fp32-reorder noise
// already proven selection-safe across 9 passing rounds.
// Epilogue: acc -> LDS rt[48][260] (D: col=lane&15 -> t, row=(lane>>4)*4+r
// -> p) -> coalesced rpart[(b*ndc+dci)][t][256] stores.
// ---------------------------------------------------------------------------
union KSMem {
  f16 stage[304 * 72];   // 43,776 B: rows 0..255 = patches, 256..303 = task
  float rt[48 * 260];    // 49,920 B: R-tile for coalesced writeback
};

__global__ __launch_bounds__(256) void k1a_partial_gemm(
    const float* __restrict__ tokens, float* __restrict__ rpart,
    float* __restrict__ ssqP, float* __restrict__ ssqT,
    float* __restrict__ out0, int ndc, int dchunk) {
  const int b = blockIdx.y;
  const int t = threadIdx.x;

  if (blockIdx.x == 0) {
    // copy cls (row 0 -> 0) and task rows (257..304 -> 129..176)
#pragma unroll 2
    for (int l = 0; l < 98; ++l) {
      int u = l * 256 + t;  // 49 rows * 512 f4
      int row = u >> 9, c = u & 511;
      int srow = (row == 0) ? 0 : (256 + row);
      int drow = (row == 0) ? 0 : (128 + row);
      *(float4*)(out0 + ((size_t)b * SOUT + drow) * DIM + (size_t)c * 4) =
          *(const float4*)(tokens + ((size_t)b * SEQ + srow) * DIM + (size_t)c * 4);
    }
    return;
  }

  const int dci = blockIdx.x - 1;
  const int lane = t & 63;
  const int wid = t >> 6;       // 0..3: m-rows wid*64..wid*64+63
  const int fr = lane & 15;     // fragment minor index
  const int g0 = (lane >> 4) * 2;  // d-group: d0 = (lane>>4)*8 = g0*4

  __shared__ __align__(16) KSMem sm;

  const float* pbase = tokens + ((size_t)b * SEQ + 1) * DIM + (size_t)dci * dchunk;
  const float* tbase = tokens + ((size_t)b * SEQ + 1 + NP) * DIM + (size_t)dci * dchunk;

  float4 st[10];
  f32x4 acc[4][3];
#pragma unroll
  for (int mf = 0; mf < 4; ++mf)
#pragma unroll
    for (int nf = 0; nf < 3; ++nf) acc[mf][nf] = (f32x4){0.f, 0.f, 0.f, 0.f};
  float ssqa[10] = {};
  const int nchunk = dchunk / 32;

  // staging map: u = t + 256*l. u<2048: p-row u>>3, c8=u&7;
  // 2048<=u<2432: task row (u-2048)>>3 (stored at 256+row).
  auto gload = [&](int ck) {
#pragma unroll
    for (int l = 0; l < 10; ++l) {
      int u = t + 256 * l;
      if (u < 2048) {
        int row = u >> 3, c8 = u & 7;
        st[l] = *(const float4*)(pbase + (size_t)row * DIM + ck * 32 + c8 * 4);
      } else if (u < 2432) {
        int v = u - 2048;
        int row = v >> 3, c8 = v & 7;
        st[l] = *(const float4*)(tbase + (size_t)row * DIM + ck * 32 + c8 * 4);
      }
    }
  };
  auto lwrite = [&]() {
#pragma unroll
    for (int l = 0; l < 10; ++l) {
      int u = t + 256 * l;
      if (u < 2432) {
        int row, c8;
        if (u < 2048) {
          row = u >> 3;
          c8 = u & 7;
        } else {
          row = 256 + ((u - 2048) >> 3);
          c8 = (u - 2048) & 7;
        }
        float4 v = st[l];
        f16 h0 = (f16)v.x, h1 = (f16)v.y, h2 = (f16)v.z, h3 = (f16)v.w;
        f16 e0 = (f16)(v.x - (float)h0), e1 = (f16)(v.y - (float)h1),
            e2 = (f16)(v.z - (float)h2), e3 = (f16)(v.w - (float)h3);
        f16x8 pk = {h0, h1, h2, h3, e0, e1, e2, e3};
        *(f16x8*)&sm.stage[row * 72 + c8 * 8] = pk;
        ssqa[l] += v.x * v.x + v.y * v.y + v.z * v.z + v.w * v.w;
      }
    }
  };

  gload(0);
  for (int ck = 0; ck < nchunk; ++ck) {
    __syncthreads();  // previous compute done reading stage
    lwrite();
    if (ck + 1 < nchunk) gload(ck + 1);  // prefetch overlaps compute
    __syncthreads();

    f16x8 bh[3], bl[3];
#pragma unroll
    for (int nf = 0; nf < 3; ++nf) {
      const f16* rowp = &sm.stage[(256 + nf * 16 + fr) * 72];
      f16x8 v1 = *(const f16x8*)(rowp + g0 * 8);
      f16x8 v2 = *(const f16x8*)(rowp + g0 * 8 + 8);
      bh[nf] = __builtin_shufflevector(v1, v2, 0, 1, 2, 3, 8, 9, 10, 11);
      bl[nf] = __builtin_shufflevector(v1, v2, 4, 5, 6, 7, 12, 13, 14, 15);
    }
#pragma unroll
    for (int mf = 0; mf < 4; ++mf) {
      const f16* rowp = &sm.stage[(wid * 64 + mf * 16 + fr) * 72];
      f16x8 v1 = *(const f16x8*)(rowp + g0 * 8);
      f16x8 v2 = *(const f16x8*)(rowp + g0 * 8 + 8);
      f16x8 ah = __builtin_shufflevector(v1, v2, 0, 1, 2, 3, 8, 9, 10, 11);
      f16x8 al = __builtin_shufflevector(v1, v2, 4, 5, 6, 7, 12, 13, 14, 15);
#pragma unroll
      for (int nf = 0; nf < 3; ++nf) {
        acc[mf][nf] =
            __builtin_amdgcn_mfma_f32_16x16x32_f16(ah, bh[nf], acc[mf][nf], 0, 0, 0);
        acc[mf][nf] =
            __builtin_amdgcn_mfma_f32_16x16x32_f16(ah, bl[nf], acc[mf][nf], 0, 0, 0);
        acc[mf][nf] =
            __builtin_amdgcn_mfma_f32_16x16x32_f16(al, bh[nf], acc[mf][nf], 0, 0, 0);
      }
    }
  }

  // epilogue: acc -> LDS rt (stage no longer needed), then coalesced stores
  __syncthreads();
#pragma unroll
  for (int mf = 0; mf < 4; ++mf)
#pragma unroll
    for (int nf = 0; nf < 3; ++nf) {
      int trow = nf * 16 + fr;                       // D col = lane&15 -> t
      int pcol = wid * 64 + mf * 16 + (lane >> 4) * 4;  // D row -> p (4 regs)
      *(float4*)&sm.rt[trow * 260 + pcol] = *(float4*)&acc[mf][nf];
    }
  __syncthreads();
  float* rp = rpart + ((size_t)b * ndc + dci) * (NT * NP);
#pragma unroll
  for (int i = 0; i < 12; ++i) {
    int f = i * 1024 + t * 4;  // 0..12287, coalesced
    int row = f >> 8, col = f & 255;
    *(float4*)(rp + f) = *(float4*)&sm.rt[row * 260 + col];
  }

  // ssq: reduce across the 8 staging lanes of each row (fixed order)
#pragma unroll
  for (int l = 0; l < 10; ++l) {
    float s = ssqa[l];
    s += __shfl_down(s, 4, 8);
    s += __shfl_down(s, 2, 8);
    s += __shfl_down(s, 1, 8);
    ssqa[l] = s;
  }
  if ((t & 7) == 0) {
#pragma unroll
    for (int l = 0; l < 10; ++l) {
      int u = t + 256 * l;
      if (u < 2048) {
        ssqP[((size_t)b * ndc + dci) * NP + (u >> 3)] = ssqa[l];
      } else if (u < 2432) {
        ssqT[((size_t)b * ndc + dci) * NT + ((u - 2048) >> 3)] = ssqa[l];
      }
    }
  }
}

// ---------------------------------------------------------------------------
// K1b: grid (16 pt, 64 b) x 256 thr, 16-row tiles. Sum ndc partials in fixed
// dci order (deterministic), rms + softmax, write attnp = softmax*invT and
// rn = raw*invP. Inits umax.
// ---------------------------------------------------------------------------
__global__ __launch_bounds__(256) void k1b_reduce_softmax(
    const float* __restrict__ rpart, const float* __restrict__ ssqP,
    const float* __restrict__ ssqT, float* __restrict__ attnp,
    float* __restrict__ rn, unsigned long long* __restrict__ umax, int ndc) {
  const int pt = blockIdx.x;  // rows pt*16..pt*16+15
  const int b = blockIdx.y;
  const int t = threadIdx.x;
  const int r = t >> 4;    // 0..15
  const int c16 = t & 15;  // cols c16*3..c16*3+2

  __shared__ float L[16][49];
  __shared__ float invPs[16];
  __shared__ float invTs[48];

  float a[3] = {};
  const float* rb = rpart + (size_t)b * ndc * (NT * NP) + pt * 16 + r;
  for (int dci = 0; dci < ndc; ++dci) {
    const float* rp = rb + (size_t)dci * (NT * NP);
#pragma unroll
    for (int k = 0; k < 3; ++k) a[k] += rp[(c16 * 3 + k) * NP];
  }
#pragma unroll
  for (int k = 0; k < 3; ++k) L[r][c16 * 3 + k] = a[k];

  if (t < 16) {
    float s = 0.f;
    for (int dci = 0; dci < ndc; ++dci)
      s += ssqP[((size_t)b * ndc + dci) * NP + pt * 16 + t];
    invPs[t] = 1.0f / sqrtf(s * (1.0f / 2048.0f) + 1e-6f);
    umax[(size_t)b * NP + pt * 16 + t] = 0ull;
  } else if (t < 64) {
    int j = t - 16;
    float s = 0.f;
    for (int dci = 0; dci < ndc; ++dci)
      s += ssqT[((size_t)b * ndc + dci) * NT + j];
    invTs[j] = 1.0f / sqrtf(s * (1.0f / 2048.0f) + 1e-6f);
  }
  __syncthreads();

  if (t < 16) {
    const float invp = invPs[t];
    float lg[48];
    float m = -3.4e38f;
#pragma unroll
    for (int j = 0; j < 48; ++j) {
      lg[j] = L[t][j] * invp * invTs[j] * kScale;
      m = fmaxf(m, lg[j]);
    }
    float s = 0.f;
#pragma unroll
    for (int j = 0; j < 48; ++j) {
      lg[j] = expf(lg[j] - m);
      s += lg[j];
    }
    const float is = 1.0f / s;
    float* ao = attnp + ((size_t)b * NP + pt * 16 + t) * NT;
    float* ro = rn + ((size_t)b * NP + pt * 16 + t) * NT;
#pragma unroll
    for (int j = 0; j < 48; ++j) ao[j] = lg[j] * is * invTs[j];
#pragma unroll
    for (int j = 0; j < 48; ++j) ro[j] = L[t][j] * invp;
  }
}

// ---------------------------------------------------------------------------
// K2: score[p][q] = sum_t attn'[p][t] * Rn[q][t], argmax over q folded in via
// packed (mono-float | ~q) atomicMax (order-independent -> deterministic).
// ---------------------------------------------------------------------------
__global__ __launch_bounds__(256) void k2_score_argmax(
    const float* __restrict__ attnp, const float* __restrict__ rn,
    unsigned long long* __restrict__ umax) {
  const int b = blockIdx.y;
  const int qt = blockIdx.x & 3;
  const int pb = blockIdx.x >> 2;
  const int t = threadIdx.x;
  const int tp = t >> 4, tq = t & 15;

  __shared__ float aS[48][68];
  __shared__ float rS[48][68];

  const float* ab = attnp + ((size_t)b * NP + pb * 64) * NT;
  const float* rb = rn + ((size_t)b * NP + qt * 64) * NT;
#pragma unroll
  for (int l = 0; l < 3; ++l) {
    int u = t + 256 * l;  // 64 rows x 12 f4
    int row = u / 12, c4 = u % 12;
    float4 v = *(const float4*)(ab + (size_t)row * NT + c4 * 4);
    aS[c4 * 4 + 0][row] = v.x;
    aS[c4 * 4 + 1][row] = v.y;
    aS[c4 * 4 + 2][row] = v.z;
    aS[c4 * 4 + 3][row] = v.w;
    float4 wv = *(const float4*)(rb + (size_t)row * NT + c4 * 4);
    rS[c4 * 4 + 0][row] = wv.x;
    rS[c4 * 4 + 1][row] = wv.y;
    rS[c4 * 4 + 2][row] = wv.z;
    rS[c4 * 4 + 3][row] = wv.w;
  }
  __syncthreads();

  float acc[4][4] = {};
#pragma unroll
  for (int k = 0; k < 48; ++k) {
    float4 av = *(const float4*)&aS[k][tp * 4];
    float4 rv = *(const float4*)&rS[k][tq * 4];
    float aa[4] = {av.x, av.y, av.z, av.w};
    float rr[4] = {rv.x, rv.y, rv.z, rv.w};
#pragma unroll
    for (int i = 0; i < 4; ++i)
#pragma unroll
      for (int j = 0; j < 4; ++j) acc[i][j] += aa[i] * rr[j];
  }

#pragma unroll
  for (int i = 0; i < 4; ++i) {
    float bs = acc[i][0];
    int bq = qt * 64 + tq * 4;
#pragma unroll
    for (int j = 1; j < 4; ++j) {
      float s = acc[i][j];
      int qq = qt * 64 + tq * 4 + j;
      if (s > bs) {  // strict > keeps smallest q on ties
        bs = s;
        bq = qq;
      }
    }
    unsigned us = __float_as_uint(bs);
    us = (us & 0x80000000u) ? ~us : (us | 0x80000000u);
    unsigned long long key =
        ((unsigned long long)us << 32) | (unsigned long long)(0xFFFFFFFFu - (unsigned)bq);
    for (int o = 8; o >= 1; o >>= 1) {
      unsigned long long ok = __shfl_xor(key, o, 16);
      if (ok > key) key = ok;
    }
    if (tq == 0) atomicMax(&umax[(size_t)b * NP + pb * 64 + tp * 4 + i], key);
  }
}

// ---------------------------------------------------------------------------
// K3: per batch: decode argmax, vote counts, exact rank (count desc, idx asc),
// keep rank<128, emit ascending; gather pos/mask in the same block.
// ---------------------------------------------------------------------------
__global__ __launch_bounds__(256) void k3_select_meta(
    const unsigned long long* __restrict__ umax, const int* __restrict__ pos,
    const int* __restrict__ msk, int* __restrict__ order,
    float* __restrict__ out1, float* __restrict__ out2) {
  const int b = blockIdx.x, t = threadIdx.x;
  __shared__ int cnt[256];
  __shared__ int kept[256];
  __shared__ int sorder[NKEEP];
  cnt[t] = 0;
  __syncthreads();
  unsigned long long key = umax[(size_t)b * NP + t];
  int q = (int)(0xFFFFFFFFu - (unsigned)(key & 0xFFFFFFFFull));
  atomicAdd(&cnt[q], 1);
  __syncthreads();
  const int c = cnt[t];
  int rank = 0;
  for (int u = 0; u < 256; ++u) {
    int cu = cnt[u];
    rank += (cu > c || (cu == c && u < t)) ? 1 : 0;
  }
  kept[t] = (rank < NKEEP) ? 1 : 0;
  __syncthreads();
  if (kept[t]) {
    int posn = 0;
    for (int u = 0; u < t; ++u) posn += kept[u];
    order[b * NKEEP + posn] = t;
    sorder[posn] = t;
  }
  __syncthreads();
  if (t < SOUT) {
    int src;
    if (t == 0) src = 0;
    else if (t < 1 + NKEEP) src = 1 + sorder[t - 1];
    else src = t + (NP - NKEEP);
    out1[b * SOUT + t] = (float)pos[b * SEQ + src];
    out2[b * SOUT + t] = (float)msk[b * SEQ + src];
  }
}

// ---------------------------------------------------------------------------
// K4: gather only the 128 kept patch rows (cls/task copied in k1a).
// ---------------------------------------------------------------------------
__global__ __launch_bounds__(256) void k4_gather_kept(
    const float* __restrict__ tokens, const int* __restrict__ order,
    float* __restrict__ out) {
  const int ki = blockIdx.x;  // 0..127
  const int b = blockIdx.y;
  const int t = threadIdx.x;
  const int src = 1 + order[b * NKEEP + ki];
  const float4* in4 = (const float4*)(tokens + ((size_t)b * SEQ + src) * DIM);
  float4* o4 = (float4*)(out + ((size_t)b * SOUT + 1 + ki) * DIM);
  o4[t] = in4[t];
  o4[t + 256] = in4[t + 256];
}

// ---------------------------------------------------------------------------
extern "C" void kernel_launch(void* const* d_in, const int* in_sizes, int n_in,
                              void* d_out, int out_size, void* d_ws,
                              size_t ws_size, hipStream_t stream) {
  const float* tokens = (const float*)d_in[0];
  const int* pos = (const int*)d_in[1];
  const int* msk = (const int*)d_in[2];

  float* out0 = (float*)d_out;
  float* out1 = out0 + (size_t)NB * SOUT * DIM;
  float* out2 = out1 + (size_t)NB * SOUT;

  // split-K depth (shrink if workspace is tight)
  const size_t fixed = (size_t)(2 * NB * NP * NT) * 4 + (size_t)NB * NP * 8 +
                       (size_t)NB * NKEEP * 4;
  const size_t perndc = (size_t)NB * (NT * NP + NP + NT) * 4;
  int ndc = 8;
  while (ndc > 2 && fixed + (size_t)ndc * perndc > ws_size) ndc >>= 1;
  const int dchunk = DIM / ndc;

  char* ws = (char*)d_ws;
  float* attnp = (float*)ws;                 // NB*NP*NT
  float* rn = attnp + (size_t)NB * NP * NT;  // NB*NP*NT
  unsigned long long* umax = (unsigned long long*)(rn + (size_t)NB * NP * NT);
  int* order = (int*)(umax + (size_t)NB * NP);
  float* rpart = (float*)(order + (size_t)NB * NKEEP);  // NB*ndc*48*256
  float* ssqP = rpart + (size_t)NB * ndc * NT * NP;     // NB*ndc*256
  float* ssqT = ssqP + (size_t)NB * ndc * NP;           // NB*ndc*48

  k1a_partial_gemm<<<dim3(1 + ndc, NB), 256, 0, stream>>>(
      tokens, rpart, ssqP, ssqT, out0, ndc, dchunk);
  k1b_reduce_softmax<<<dim3(16, NB), 256, 0, stream>>>(rpart, ssqP, ssqT, attnp,
                                                       rn, umax, ndc);
  k2_score_argmax<<<dim3(16, NB), 256, 0, stream>>>(attnp, rn, umax);
  k3_select_meta<<<NB, 256, 0, stream>>>(umax, pos, msk, order, out1, out2);
  k4_gather_kept<<<dim3(NKEEP, NB), 256, 0, stream>>>(tokens, order, out0);
}